// Round 5
// baseline (1952.212 us; speedup 1.0000x reference)
//
#include <hip/hip_runtime.h>
#include <hip/hip_bf16.h>
#include <math.h>

#define LNUM  6
#define HDIM  768
#define NHEAD 12
#define DHEAD 64
#define IDIM  3072
#define NB    16
#define SEQ   512
#define MTOK  (NB*SEQ)   // 8192
#define NQKV  (3*HDIM)   // 2304

typedef __bf16 bf16;
typedef __bf16 bf16x4 __attribute__((ext_vector_type(4)));
typedef __bf16 bf16x8 __attribute__((ext_vector_type(8)));
typedef float  f32x4  __attribute__((ext_vector_type(4)));

__device__ __forceinline__ void async_copy16(const bf16* g, bf16* l) {
  __builtin_amdgcn_global_load_lds((__attribute__((address_space(1))) void*)g,
                                   (__attribute__((address_space(3))) void*)l,
                                   16, 0, 0);
}

// fast gelu (tanh form): max abs err vs exact-erf gelu ~3e-3
__device__ __forceinline__ float gelu_fast(float t) {
  const float u = 0.7978845608f * (t + 0.044715f * t * t * t);
  const float e = __expf(-2.f * fabsf(u));
  const float th = (1.f - e) / (1.f + e);
  return 0.5f * t * (1.f + copysignf(th, u));
}

// =====================  dtype detector (f32 vs bf16 input)  ==================
__global__ void detect_k(const unsigned short* __restrict__ probe, int* __restrict__ flag)
{
  __shared__ int sc[4];
  const int tid = threadIdx.x;
  int cnt = 0;
#pragma unroll
  for (int j = 0; j < 16; j++) {
    const unsigned short w = probe[tid * 16 + j];
    const int e = (w >> 7) & 0xFF;
    cnt += (e >= 90 && e <= 130) ? 1 : 0;
  }
#pragma unroll
  for (int o = 32; o; o >>= 1) cnt += __shfl_xor(cnt, o);
  if ((tid & 63) == 0) sc[tid >> 6] = cnt;
  __syncthreads();
  if (tid == 0) flag[0] = ((sc[0] + sc[1] + sc[2] + sc[3]) < 3482) ? 1 : 0;
}

// =====================  normalize copies  =====================
__global__ void cvt1d_k(const void* __restrict__ src, bf16* __restrict__ dst,
                        int n, const int* __restrict__ flag)
{
  const int i = blockIdx.x * 256 + threadIdx.x;
  if (i < n)
    dst[i] = (*flag) ? (bf16)((const float*)src)[i] : ((const bf16*)src)[i];
}

// slice-copy [L][perL] -> dst[l*dstStride + off + c]   (for qkv bias concat)
__global__ void cvt_slice_k(const void* __restrict__ src, bf16* __restrict__ dst,
                            int perL, int off, int dstStride, int total,
                            const int* __restrict__ flag)
{
  const int i = blockIdx.x * 256 + threadIdx.x;
  if (i < total) {
    const int l = i / perL, c = i - l * perL;
    const bf16 v = (*flag) ? (bf16)((const float*)src)[i] : ((const bf16*)src)[i];
    dst[l * dstStride + off + c] = v;
  }
}

// ====  weight transpose+normalize: (K x N) -> (N x K) bf16, strided dst  =====
__global__ void wtrans_k(const void* __restrict__ src, bf16* __restrict__ dst,
                         int K, int N, int layer, int dstLS, int dstOff,
                         const int* __restrict__ flag)
{
  __shared__ bf16 t[32][33];
  const size_t sOff = (size_t)(blockIdx.z + layer) * K * N;
  const size_t dOff = (size_t)blockIdx.z * dstLS + dstOff;
  const int n0 = blockIdx.x * 32, k0 = blockIdx.y * 32;
  const int tx = threadIdx.x, ty = threadIdx.y;   // (32,8)
  const int f = *flag;
#pragma unroll
  for (int i = 0; i < 4; i++) {
    const size_t idx = sOff + (size_t)(k0 + ty*4 + i) * N + n0 + tx;
    t[ty*4+i][tx] = f ? (bf16)((const float*)src)[idx] : ((const bf16*)src)[idx];
  }
  __syncthreads();
#pragma unroll
  for (int i = 0; i < 4; i++)
    dst[dOff + (size_t)(n0 + ty*4 + i) * K + k0 + tx] = t[tx][ty*4+i];
}

// =====================  MFMA GEMM, B^T (N x K) input, 4-buf 1-barrier  =======
// ROUND-5: 4 LDS buffers, stage-distance 2, ONE barrier per 32-K step.
// r4 (3-buf, 2 barriers/step) measured ~1200 cyc/CU-step vs ~1150 resource
// floor but MfmaUtil only 22% -> pipes not overlapping; barriers gang all 12
// waves twice per step and vmcnt cover (~1 step) was marginal vs HBM-miss
// latency (~900cy; FETCH 66MB/dispatch = real misses).
// Single-barrier correctness: dst buffer at step t is buf((t+2)%4), last
// read at step t-2. A wave issuing STAGE(t) has passed barrier(t-1); every
// wave reaching barrier(t-1) finished COMP(t-2)'s ds_reads (MFMA consumption
// forces lgkm). So barrier(t-1) certifies dst reads complete. vmcnt(8)
// (= 2 stages x 4 loads in flight) before barrier(t) => at release, ALL
// waves' tile-t loads have landed. Prefetch depth 2 steps (~2400cy cover).
// Tail: clamped redundant re-stage keeps counts uniform, stays in-bounds.
// LDS 4 x 16KB = 64KB -> 2 blocks/CU. Requires K % 128 == 0 (768, 3072 ok).
// LDS tile layout per buffer: 16B slot s of a 64-row block holds
//   (row = s>>2, kgroup = (s&3) ^ ((s>>3)&3))   [XOR swizzle, conflict-free]
// EPI: 2 = fp32 acc+bias+res_bf16 -> Cf
//      3 = bf16 gelu_fast(acc+bias) -> Cb
//      5 = fused QKV routing: nn<768 -> Cb=q (*0.125); <1536 -> Cb2=k;
//          else Cb3 = v^T per-head [((b*NH+h)*DH+d)*SEQ+s]
// XS: 1 = XCD-aware block swizzle (requires gridDim.y % 8 == 0)
#define STAGE4(DA, DB, KK) do {                                                \
    const int kk_ = ((KK) < K) ? (KK) : (K - 32);                              \
    _Pragma("unroll")                                                          \
    for (int p = 0; p < BM/64; p++)                                            \
      async_copy16(gA + (size_t)p * 64 * sA + kk_,                             \
                   &DA[(wave*16)*32 + p*64*32]);                               \
    _Pragma("unroll")                                                          \
    for (int p = 0; p < BN/64; p++)                                            \
      async_copy16(gB + (size_t)p * 64 * sB + kk_,                             \
                   &DB[(wave*16)*32 + p*64*32]);                               \
  } while (0)

#define COMP4(SA, SB) do {                                                     \
    bf16x8 af[MT], bfv[NT];                                                    \
    _Pragma("unroll")                                                          \
    for (int i = 0; i < MT; i++)                                               \
      af[i] = *(const bf16x8*)&SA[(wm*(MT*16) + i*16 + l16) * 32               \
                                  + (quad ^ swz) * 8];                         \
    _Pragma("unroll")                                                          \
    for (int j = 0; j < NT; j++)                                               \
      bfv[j] = *(const bf16x8*)&SB[(wn*(NT*16) + j*16 + l16) * 32              \
                                   + (quad ^ swz) * 8];                        \
    _Pragma("unroll")                                                          \
    for (int i = 0; i < MT; i++)                                               \
      _Pragma("unroll")                                                        \
      for (int j = 0; j < NT; j++)                                             \
        acc[i][j] = __builtin_amdgcn_mfma_f32_16x16x32_bf16(                   \
            af[i], bfv[j], acc[i][j], 0, 0, 0);                                \
  } while (0)

// one step: stage tile(t+2) -> vmcnt(8) -> barrier -> compute tile(t)
#define PIPE_STEP4(SA, SB, DA, DB, KK) do {                                    \
    STAGE4(DA, DB, KK);                                                        \
    asm volatile("s_waitcnt vmcnt(8)" ::: "memory");                           \
    __builtin_amdgcn_s_barrier();                                              \
    COMP4(SA, SB);                                                             \
  } while (0)

template<int BM, int BN, int MT, int NT, int EPI, int XS>
__global__ __launch_bounds__(256, 2)
void gemm_bt(const bf16* __restrict__ A, const bf16* __restrict__ Bt,
             float* __restrict__ Cf, bf16* __restrict__ Cb,
             bf16* __restrict__ Cb2, bf16* __restrict__ Cb3,
             const bf16* __restrict__ bias, const bf16* __restrict__ res,
             int K, int sA, int sB, int sC)
{
  __shared__ __align__(16) bf16 A0[BM*32];
  __shared__ __align__(16) bf16 B0[BN*32];
  __shared__ __align__(16) bf16 A1[BM*32];
  __shared__ __align__(16) bf16 B1[BN*32];
  __shared__ __align__(16) bf16 A2[BM*32];
  __shared__ __align__(16) bf16 B2[BN*32];
  __shared__ __align__(16) bf16 A3[BM*32];
  __shared__ __align__(16) bf16 B3[BN*32];
  const int tid  = threadIdx.x;
  const int wave = tid >> 6;
  const int lane = tid & 63;
  const int quad = lane >> 4;
  const int l16  = lane & 15;
  const int wm = wave >> 1, wn = wave & 1;   // 2x2 wave grid
  const int swz = (l16 >> 1) & 3;            // read-side XOR swizzle key

  int bx = blockIdx.x, by = blockIdx.y;
  if (XS) {
    if ((gridDim.y & 7) == 0) {
      const int id  = by * gridDim.x + bx;
      const int xcd = id & 7, slot = id >> 3;
      bx = slot % gridDim.x;
      by = (slot / gridDim.x) * 8 + xcd;
    }
  }
  const int m0 = by * BM;
  const int n0 = bx * BN;
  const int srow = tid >> 2;
  const int scol = (((tid & 3) ^ ((tid >> 3) & 3))) * 8;   // swizzled gather

  const bf16* gA = A + (size_t)(m0 + srow) * sA + scol;
  const bf16* gB = Bt + (size_t)(n0 + srow) * sB + scol;

  f32x4 acc[MT][NT];
  const f32x4 fzero = {0.f, 0.f, 0.f, 0.f};
#pragma unroll
  for (int i = 0; i < MT; i++)
#pragma unroll
    for (int j = 0; j < NT; j++) acc[i][j] = fzero;

  // ---- 4-stage software pipeline, depth 2, 1 barrier/step (K % 128 == 0) --
  STAGE4(A0, B0, 0);
  STAGE4(A1, B1, 32);
  for (int k0 = 0; k0 < K; k0 += 128) {
    PIPE_STEP4(A0, B0, A2, B2, k0 + 64);
    PIPE_STEP4(A1, B1, A3, B3, k0 + 96);
    PIPE_STEP4(A2, B2, A0, B0, k0 + 128);
    PIPE_STEP4(A3, B3, A1, B1, k0 + 160);
  }
  asm volatile("s_waitcnt vmcnt(0)" ::: "memory");   // drain redundant tail DMA

  // epilogue: C/D layout col=lane&15, row=quad*4+reg
#pragma unroll
  for (int i = 0; i < MT; i++) {
    const int mtile = m0 + wm*(MT*16) + i*16 + quad*4;
#pragma unroll
    for (int j = 0; j < NT; j++) {
      const int nn = n0 + wn*(NT*16) + j*16 + l16;
      const float bv = bias ? (float)bias[nn] : 0.f;
      if (EPI == 5) {
        if (nn < HDIM) {
#pragma unroll
          for (int r = 0; r < 4; r++)
            Cb[(size_t)(mtile + r) * HDIM + nn] = (bf16)((acc[i][j][r] + bv) * 0.125f);
        } else if (nn < 2*HDIM) {
#pragma unroll
          for (int r = 0; r < 4; r++)
            Cb2[(size_t)(mtile + r) * HDIM + (nn - HDIM)] = (bf16)(acc[i][j][r] + bv);
        } else {
          const int nn2 = nn - 2*HDIM;
          const int bb = mtile >> 9, s = mtile & 511;
          const int hh = nn2 >> 6, dd = nn2 & 63;
          const size_t base = ((size_t)(bb*NHEAD + hh) * DHEAD + dd) * SEQ + s;
          bf16x4 pk;
#pragma unroll
          for (int r = 0; r < 4; r++) pk[r] = (bf16)(acc[i][j][r] + bv);
          *(bf16x4*)(Cb3 + base) = pk;
        }
      } else {
#pragma unroll
        for (int r = 0; r < 4; r++) {
          const int mm = mtile + r;
          const size_t idx = (size_t)mm * sC + nn;
          const float v = acc[i][j][r];
          if (EPI == 2) Cf[idx] = v + bv + (float)res[idx];
          else if (EPI == 3) Cb[idx] = (bf16)gelu_fast(v + bv);
        }
      }
    }
  }
}

// =====================  fused flash attention  =====================
__global__ __launch_bounds__(256)
void flash_k(const bf16* __restrict__ qb, const bf16* __restrict__ kb,
             const bf16* __restrict__ vt, bf16* __restrict__ ctxb)
{
  __shared__ __align__(16) bf16 Qs[128][72];
  __shared__ __align__(16) bf16 Ks[64][72];
  __shared__ __align__(16) bf16 Vs[64][72];
  __shared__ __align__(16) bf16 Ps[128][72];
  const int tid = threadIdx.x;
  const int wave = tid >> 6, lane = tid & 63;
  const int quad = lane >> 4, l16 = lane & 15;
  const int z = blockIdx.y;
  const int b = z / NHEAD, h = z - b * NHEAD;
  const int qt = blockIdx.x;
  const size_t qRow0 = (size_t)b * SEQ + qt * 128;

#pragma unroll
  for (int r = 0; r < 4; r++) {
    const int idx = tid + r * 256;
    const int row = idx >> 3, c8 = (idx & 7) * 8;
    *(bf16x8*)&Qs[row][c8] =
        *(const bf16x8*)&qb[(qRow0 + row) * HDIM + h * DHEAD + c8];
  }

  f32x4 Oacc[2][4];
  float mrow[2][4], lrow[2][4];
#pragma unroll
  for (int i = 0; i < 2; i++)
#pragma unroll
    for (int n = 0; n < 4; n++) Oacc[i][n] = (f32x4){0.f,0.f,0.f,0.f};
#pragma unroll
  for (int i = 0; i < 2; i++)
#pragma unroll
    for (int r = 0; r < 4; r++) { mrow[i][r] = -3.0e38f; lrow[i][r] = 0.f; }

  for (int j = 0; j < 8; j++) {
    __syncthreads();
#pragma unroll
    for (int r = 0; r < 2; r++) {
      const int idx = tid + r * 256;
      const int row = idx >> 3, c8 = (idx & 7) * 8;
      *(bf16x8*)&Ks[row][c8] =
          *(const bf16x8*)&kb[((size_t)b*SEQ + j*64 + row) * HDIM + h*DHEAD + c8];
      *(bf16x8*)&Vs[row][c8] =
          *(const bf16x8*)&vt[((size_t)z*DHEAD + row) * SEQ + j*64 + c8];
    }
    __syncthreads();

    f32x4 Sacc[2][4];
#pragma unroll
    for (int i = 0; i < 2; i++)
#pragma unroll
      for (int n = 0; n < 4; n++) Sacc[i][n] = (f32x4){0.f,0.f,0.f,0.f};
#pragma unroll
    for (int kk = 0; kk < 2; kk++) {
      bf16x8 af[2], bv[4];
#pragma unroll
      for (int i = 0; i < 2; i++)
        af[i] = *(const bf16x8*)&Qs[wave*32 + i*16 + l16][kk*32 + quad*8];
#pragma unroll
      for (int n = 0; n < 4; n++)
        bv[n] = *(const bf16x8*)&Ks[n*16 + l16][kk*32 + quad*8];
#pragma unroll
      for (int i = 0; i < 2; i++)
#pragma unroll
        for (int n = 0; n < 4; n++)
          Sacc[i][n] = __builtin_amdgcn_mfma_f32_16x16x32_bf16(af[i], bv[n], Sacc[i][n], 0,0,0);
    }

    float alpha[2][4];
#pragma unroll
    for (int i = 0; i < 2; i++)
#pragma unroll
      for (int r = 0; r < 4; r++) {
        float mx = Sacc[i][0][r];
#pragma unroll
        for (int n = 1; n < 4; n++) mx = fmaxf(mx, Sacc[i][n][r]);
#pragma unroll
        for (int o = 8; o; o >>= 1) mx = fmaxf(mx, __shfl_xor(mx, o));
        const float mn = fmaxf(mrow[i][r], mx);
        const float a = __expf(mrow[i][r] - mn);
        float rs = 0.f;
#pragma unroll
        for (int n = 0; n < 4; n++) {
          const float p = __expf(Sacc[i][n][r] - mn);
          Sacc[i][n][r] = p; rs += p;
        }
#pragma unroll
        for (int o = 8; o; o >>= 1) rs += __shfl_xor(rs, o);
        lrow[i][r] = lrow[i][r] * a + rs;
        mrow[i][r] = mn;
        alpha[i][r] = a;
      }

#pragma unroll
    for (int i = 0; i < 2; i++)
#pragma unroll
      for (int n = 0; n < 4; n++)
#pragma unroll
        for (int r = 0; r < 4; r++)
          Ps[wave*32 + i*16 + quad*4 + r][n*16 + l16] = (bf16)Sacc[i][n][r];
    __syncthreads();

#pragma unroll
    for (int i = 0; i < 2; i++)
#pragma unroll
      for (int n = 0; n < 4; n++)
#pragma unroll
        for (int r = 0; r < 4; r++) Oacc[i][n][r] *= alpha[i][r];
#pragma unroll
    for (int kk = 0; kk < 2; kk++) {
      bf16x8 af[2], bv[4];
#pragma unroll
      for (int i = 0; i < 2; i++)
        af[i] = *(const bf16x8*)&Ps[wave*32 + i*16 + l16][kk*32 + quad*8];
#pragma unroll
      for (int n = 0; n < 4; n++)
        bv[n] = *(const bf16x8*)&Vs[n*16 + l16][kk*32 + quad*8];
#pragma unroll
      for (int i = 0; i < 2; i++)
#pragma unroll
        for (int n = 0; n < 4; n++)
          Oacc[i][n] = __builtin_amdgcn_mfma_f32_16x16x32_bf16(af[i], bv[n], Oacc[i][n], 0,0,0);
    }
  }

#pragma unroll
  for (int i = 0; i < 2; i++)
#pragma unroll
    for (int r = 0; r < 4; r++) {
      const float inv = 1.f / lrow[i][r];
      const size_t tok = qRow0 + wave*32 + i*16 + quad*4 + r;
#pragma unroll
      for (int n = 0; n < 4; n++)
        ctxb[tok * HDIM + h*DHEAD + n*16 + l16] = (bf16)(Oacc[i][n][r] * inv);
    }
}

// ========  LayerNorm over H=768, fp32 in, bf16 out (+ optional d_out)  ========
__global__ void layernorm_k(const float* __restrict__ x, const bf16* __restrict__ g,
                            const bf16* __restrict__ b, bf16* __restrict__ yb,
                            void* __restrict__ dout, int last, const int* __restrict__ flag)
{
  __shared__ float sred[4];
  const int row = blockIdx.x;
  const int tid = threadIdx.x;
  const float* xr = x + (size_t)row * HDIM;
  const float v0 = xr[tid], v1 = xr[tid+256], v2 = xr[tid+512];
  float s = v0 + v1 + v2;
#pragma unroll
  for (int o = 32; o; o >>= 1) s += __shfl_xor(s, o);
  if ((tid & 63) == 0) sred[tid >> 6] = s;
  __syncthreads();
  const float mean = (sred[0]+sred[1]+sred[2]+sred[3]) * (1.f/768.f);
  __syncthreads();
  const float d0 = v0-mean, d1 = v1-mean, d2 = v2-mean;
  float vs = d0*d0 + d1*d1 + d2*d2;
#pragma unroll
  for (int o = 32; o; o >>= 1) vs += __shfl_xor(vs, o);
  if ((tid & 63) == 0) sred[tid >> 6] = vs;
  __syncthreads();
  const float var = (sred[0]+sred[1]+sred[2]+sred[3]) * (1.f/768.f);
  const float rs  = rsqrtf(var + 1e-12f);
  const float y0 = d0*rs*(float)g[tid]     + (float)b[tid];
  const float y1 = d1*rs*(float)g[tid+256] + (float)b[tid+256];
  const float y2 = d2*rs*(float)g[tid+512] + (float)b[tid+512];
  bf16* ybr = yb + (size_t)row * HDIM;
  ybr[tid]     = (bf16)y0;
  ybr[tid+256] = (bf16)y1;
  ybr[tid+512] = (bf16)y2;
  if (last) {
    if (*flag) {
      float* o = (float*)dout + (size_t)row * HDIM;
      o[tid] = y0; o[tid+256] = y1; o[tid+512] = y2;
    } else {
      bf16* o = (bf16*)dout + (size_t)row * HDIM;
      o[tid] = (bf16)y0; o[tid+256] = (bf16)y1; o[tid+512] = (bf16)y2;
    }
  }
}

// ============================================================================
extern "C" void kernel_launch(void* const* d_in, const int* in_sizes, int n_in,
                              void* d_out, int out_size, void* d_ws, size_t ws_size,
                              hipStream_t stream)
{
  (void)in_sizes; (void)n_in; (void)out_size;

  char* ws = (char*)d_ws;
  size_t off = 0;
  auto carve = [&](size_t bytes) -> char* {
    char* p = ws + off; off += (bytes + 255) & ~(size_t)255; return p;
  };
  int*   flag = (int*)carve(256);
  bf16*  hcur = (bf16*)carve((size_t)MTOK*HDIM*2);
  bf16*  qb   = (bf16*)carve((size_t)MTOK*HDIM*2);
  bf16*  kb   = (bf16*)carve((size_t)MTOK*HDIM*2);
  bf16*  vt   = (bf16*)carve((size_t)MTOK*HDIM*2);
  bf16*  ctxb = (bf16*)carve((size_t)MTOK*HDIM*2);
  float* x1   = (float*)carve((size_t)MTOK*HDIM*4);
  bf16*  aob  = kb;   // kb dead once flash attention of the layer is complete

  bf16* nbqkv = (bf16*)carve((size_t)LNUM*NQKV*2);
  bf16* nbo   = (bf16*)carve((size_t)LNUM*HDIM*2);
  bf16* ng1   = (bf16*)carve((size_t)LNUM*HDIM*2);
  bf16* nb1   = (bf16*)carve((size_t)LNUM*HDIM*2);
  bf16* nbi   = (bf16*)carve((size_t)LNUM*IDIM*2);
  bf16* nbo2  = (bf16*)carve((size_t)LNUM*HDIM*2);
  bf16* ng2   = (bf16*)carve((size_t)LNUM*HDIM*2);
  bf16* nb2   = (bf16*)carve((size_t)LNUM*HDIM*2);

  const size_t wAllBytes = (size_t)LNUM*(NQKV*HDIM + HDIM*HDIM + 2*HDIM*IDIM)*2; // ~84.9MB
  const bool preAll = ws_size >= off + wAllBytes + (size_t)256*IDIM*2 + (1u<<20);
  bf16 *wqkvt=0, *wot=0, *wit=0, *wo2t=0, *bufA=0, *bufB=0;
  if (preAll) {
    wqkvt = (bf16*)carve((size_t)LNUM*NQKV*HDIM*2);
    wot   = (bf16*)carve((size_t)LNUM*HDIM*HDIM*2);
    wit   = (bf16*)carve((size_t)LNUM*HDIM*IDIM*2);
    wo2t  = (bf16*)carve((size_t)LNUM*HDIM*IDIM*2);
  } else {
    bufA = (bf16*)carve((size_t)HDIM*IDIM*2);
    bufB = (bf16*)carve((size_t)HDIM*IDIM*2);
  }

  const size_t unionAvail = (ws_size > off) ? (ws_size - off) : 0;
  int RM = 256;
  { const int rms[6] = {8192,4096,2048,1024,512,256};
    for (int i = 0; i < 6; i++)
      if ((size_t)rms[i]*IDIM*2 <= unionAvail) { RM = rms[i]; break; } }
  bf16* interb = (bf16*)(ws + off);

  // ---------------- normalize inputs ----------------------------------------
  detect_k<<<1, 256, 0, stream>>>((const unsigned short*)d_in[1], flag);
  cvt1d_k<<<(MTOK*HDIM+255)/256, 256, 0, stream>>>(d_in[0], hcur, MTOK*HDIM, flag);
  cvt_slice_k<<<(LNUM*HDIM+255)/256, 256, 0, stream>>>(d_in[2], nbqkv, HDIM, 0,      NQKV, LNUM*HDIM, flag);
  cvt_slice_k<<<(LNUM*HDIM+255)/256, 256, 0, stream>>>(d_in[4], nbqkv, HDIM, HDIM,   NQKV, LNUM*HDIM, flag);
  cvt_slice_k<<<(LNUM*HDIM+255)/256, 256, 0, stream>>>(d_in[6], nbqkv, HDIM, 2*HDIM, NQKV, LNUM*HDIM, flag);
  cvt1d_k<<<(LNUM*HDIM+255)/256, 256, 0, stream>>>(d_in[8],  nbo,  LNUM*HDIM, flag);
  cvt1d_k<<<(LNUM*HDIM+255)/256, 256, 0, stream>>>(d_in[9],  ng1,  LNUM*HDIM, flag);
  cvt1d_k<<<(LNUM*HDIM+255)/256, 256, 0, stream>>>(d_in[10], nb1,  LNUM*HDIM, flag);
  cvt1d_k<<<(LNUM*IDIM+255)/256, 256, 0, stream>>>(d_in[12], nbi,  LNUM*IDIM, flag);
  cvt1d_k<<<(LNUM*HDIM+255)/256, 256, 0, stream>>>(d_in[14], nbo2, LNUM*HDIM, flag);
  cvt1d_k<<<(LNUM*HDIM+255)/256, 256, 0, stream>>>(d_in[15], ng2,  LNUM*HDIM, flag);
  cvt1d_k<<<(LNUM*HDIM+255)/256, 256, 0, stream>>>(d_in[16], nb2,  LNUM*HDIM, flag);

  const dim3 tb(32, 8);
  if (preAll) {
    wtrans_k<<<dim3(HDIM/32, HDIM/32, LNUM), tb, 0, stream>>>(d_in[1], wqkvt, HDIM, HDIM, 0, NQKV*HDIM, 0,           flag);
    wtrans_k<<<dim3(HDIM/32, HDIM/32, LNUM), tb, 0, stream>>>(d_in[3], wqkvt, HDIM, HDIM, 0, NQKV*HDIM, HDIM*HDIM,   flag);
    wtrans_k<<<dim3(HDIM/32, HDIM/32, LNUM), tb, 0, stream>>>(d_in[5], wqkvt, HDIM, HDIM, 0, NQKV*HDIM, 2*HDIM*HDIM, flag);
    wtrans_k<<<dim3(HDIM/32, HDIM/32, LNUM), tb, 0, stream>>>(d_in[7], wot,  HDIM, HDIM, 0, HDIM*HDIM, 0, flag);
    wtrans_k<<<dim3(IDIM/32, HDIM/32, LNUM), tb, 0, stream>>>(d_in[11], wit,  HDIM, IDIM, 0, HDIM*IDIM, 0, flag);
    wtrans_k<<<dim3(HDIM/32, IDIM/32, LNUM), tb, 0, stream>>>(d_in[13], wo2t, IDIM, HDIM, 0, HDIM*IDIM, 0, flag);
  }

  for (int l = 0; l < LNUM; l++) {
    const bf16* hin = hcur;

    // ---- fused QKV ----
    const bf16* WqkvT;
    if (preAll) WqkvT = wqkvt + (size_t)l * NQKV * HDIM;
    else {
      wtrans_k<<<dim3(HDIM/32, HDIM/32, 1), tb, 0, stream>>>(d_in[1], bufA, HDIM, HDIM, l, 0, 0,           flag);
      wtrans_k<<<dim3(HDIM/32, HDIM/32, 1), tb, 0, stream>>>(d_in[3], bufA, HDIM, HDIM, l, 0, HDIM*HDIM,   flag);
      wtrans_k<<<dim3(HDIM/32, HDIM/32, 1), tb, 0, stream>>>(d_in[5], bufA, HDIM, HDIM, l, 0, 2*HDIM*HDIM, flag);
      WqkvT = bufA;
    }
    gemm_bt<128,128,4,4,5,1><<<dim3(NQKV/128, MTOK/128), 256, 0, stream>>>(
        hin, WqkvT, nullptr, qb, kb, vt, nbqkv + (size_t)l*NQKV, nullptr,
        HDIM, HDIM, HDIM, HDIM);

    // ---- fused flash attention ----
    flash_k<<<dim3(SEQ/128, NB*NHEAD), 256, 0, stream>>>(qb, kb, vt, ctxb);

    // ---- x1 = ctx@Wo + bo + h ; attn_out = LN(x1) -> aob ----
    const bf16* WoT;
    if (preAll) WoT = wot + (size_t)l * HDIM * HDIM;
    else {
      wtrans_k<<<dim3(HDIM/32, HDIM/32, 1), tb, 0, stream>>>(d_in[7], bufA, HDIM, HDIM, l, 0, 0, flag);
      WoT = bufA;
    }
    gemm_bt<128,128,4,4,2,1><<<dim3(HDIM/128, MTOK/128), 256, 0, stream>>>(
        ctxb, WoT, x1, nullptr, nullptr, nullptr, nbo + l*HDIM, hin,
        HDIM, HDIM, HDIM, HDIM);
    layernorm_k<<<MTOK, 256, 0, stream>>>(x1, ng1 + l*HDIM, nb1 + l*HDIM, aob,
                                          d_out, 0, flag);

    // ---- FFN ----
    const bf16 *WiT, *Wo2T;
    if (preAll) { WiT = wit + (size_t)l*HDIM*IDIM; Wo2T = wo2t + (size_t)l*HDIM*IDIM; }
    else {
      wtrans_k<<<dim3(IDIM/32, HDIM/32, 1), tb, 0, stream>>>(d_in[11], bufA, HDIM, IDIM, l, 0, 0, flag);
      wtrans_k<<<dim3(HDIM/32, IDIM/32, 1), tb, 0, stream>>>(d_in[13], bufB, IDIM, HDIM, l, 0, 0, flag);
      WiT = bufA; Wo2T = bufB;
    }
    for (int r0 = 0; r0 < MTOK; r0 += RM) {
      gemm_bt<128,128,4,4,3,1><<<dim3(IDIM/128, RM/128), 256, 0, stream>>>(
          aob + (size_t)r0*HDIM, WiT, nullptr, interb, nullptr, nullptr,
          nbi + (size_t)l*IDIM, nullptr, HDIM, HDIM, HDIM, IDIM);
      gemm_bt<128,128,4,4,2,1><<<dim3(HDIM/128, RM/128), 256, 0, stream>>>(
          interb, Wo2T, x1 + (size_t)r0*HDIM, nullptr, nullptr, nullptr,
          nbo2 + l*HDIM, aob + (size_t)r0*HDIM, IDIM, IDIM, IDIM, HDIM);
    }
    layernorm_k<<<MTOK, 256, 0, stream>>>(x1, ng2 + l*HDIM, nb2 + l*HDIM, hcur,
                                          d_out, (l == LNUM-1) ? 1 : 0, flag);
  }
}

// Round 6
// 1796.587 us; speedup vs baseline: 1.0866x; 1.0866x over previous
//
#include <hip/hip_runtime.h>
#include <hip/hip_bf16.h>
#include <math.h>

#define LNUM  6
#define HDIM  768
#define NHEAD 12
#define DHEAD 64
#define IDIM  3072
#define NB    16
#define SEQ   512
#define MTOK  (NB*SEQ)   // 8192
#define NQKV  (3*HDIM)   // 2304

typedef __bf16 bf16;
typedef __bf16 bf16x4 __attribute__((ext_vector_type(4)));
typedef __bf16 bf16x8 __attribute__((ext_vector_type(8)));
typedef float  f32x4  __attribute__((ext_vector_type(4)));

__device__ __forceinline__ void async_copy16(const bf16* g, bf16* l) {
  __builtin_amdgcn_global_load_lds((__attribute__((address_space(1))) void*)g,
                                   (__attribute__((address_space(3))) void*)l,
                                   16, 0, 0);
}

// fast gelu (tanh form): max abs err vs exact-erf gelu ~3e-3
__device__ __forceinline__ float gelu_fast(float t) {
  const float u = 0.7978845608f * (t + 0.044715f * t * t * t);
  const float e = __expf(-2.f * fabsf(u));
  const float th = (1.f - e) / (1.f + e);
  return 0.5f * t * (1.f + copysignf(th, u));
}

// =====================  dtype detector (f32 vs bf16 input)  ==================
__global__ void detect_k(const unsigned short* __restrict__ probe, int* __restrict__ flag)
{
  __shared__ int sc[4];
  const int tid = threadIdx.x;
  int cnt = 0;
#pragma unroll
  for (int j = 0; j < 16; j++) {
    const unsigned short w = probe[tid * 16 + j];
    const int e = (w >> 7) & 0xFF;
    cnt += (e >= 90 && e <= 130) ? 1 : 0;
  }
#pragma unroll
  for (int o = 32; o; o >>= 1) cnt += __shfl_xor(cnt, o);
  if ((tid & 63) == 0) sc[tid >> 6] = cnt;
  __syncthreads();
  if (tid == 0) flag[0] = ((sc[0] + sc[1] + sc[2] + sc[3]) < 3482) ? 1 : 0;
}

// =====================  normalize copies  =====================
__global__ void cvt1d_k(const void* __restrict__ src, bf16* __restrict__ dst,
                        int n, const int* __restrict__ flag)
{
  const int i = blockIdx.x * 256 + threadIdx.x;
  if (i < n)
    dst[i] = (*flag) ? (bf16)((const float*)src)[i] : ((const bf16*)src)[i];
}

// slice-copy [L][perL] -> dst[l*dstStride + off + c]   (for qkv bias concat)
__global__ void cvt_slice_k(const void* __restrict__ src, bf16* __restrict__ dst,
                            int perL, int off, int dstStride, int total,
                            const int* __restrict__ flag)
{
  const int i = blockIdx.x * 256 + threadIdx.x;
  if (i < total) {
    const int l = i / perL, c = i - l * perL;
    const bf16 v = (*flag) ? (bf16)((const float*)src)[i] : ((const bf16*)src)[i];
    dst[l * dstStride + off + c] = v;
  }
}

// ====  weight transpose+normalize: (K x N) -> (N x K) bf16, strided dst  =====
__global__ void wtrans_k(const void* __restrict__ src, bf16* __restrict__ dst,
                         int K, int N, int layer, int dstLS, int dstOff,
                         const int* __restrict__ flag)
{
  __shared__ bf16 t[32][33];
  const size_t sOff = (size_t)(blockIdx.z + layer) * K * N;
  const size_t dOff = (size_t)blockIdx.z * dstLS + dstOff;
  const int n0 = blockIdx.x * 32, k0 = blockIdx.y * 32;
  const int tx = threadIdx.x, ty = threadIdx.y;   // (32,8)
  const int f = *flag;
#pragma unroll
  for (int i = 0; i < 4; i++) {
    const size_t idx = sOff + (size_t)(k0 + ty*4 + i) * N + n0 + tx;
    t[ty*4+i][tx] = f ? (bf16)((const float*)src)[idx] : ((const bf16*)src)[idx];
  }
  __syncthreads();
#pragma unroll
  for (int i = 0; i < 4; i++)
    dst[dOff + (size_t)(n0 + ty*4 + i) * K + k0 + tx] = t[tx][ty*4+i];
}

// =====================  MFMA GEMM, B^T (N x K) input, 3-stage pipeline  ======
// ROUND-6: exact r4 pipeline (best measured: 3-buf, depth-2, 2 barriers/step,
// 48KB LDS -> 3 blocks/CU; r5's 1-barrier/4-buf traded occupancy 3->2 and
// regressed) + two additions:
//   (a) s_setprio(1/0) around the MFMA cluster (T5; phase-diverse blocks).
//   (b) split-K via gridDim.z: z=1 offsets A/Bt by `ksplit` cols and writes
//       partials to Cf2. Fixes the N=768 fill problem (Wo/Wo2 were 384
//       blocks = 50% CU fill; now 768 = 256CUx3 = 100% in ONE dispatch).
//       Partial sum + bias + residual folds into layernorm2_k.
// Per step: STAGE(t+2) -> vmcnt(4) [retires stage(t+1), keeps t+2 in
// flight] -> barrier -> COMP(t) -> barrier.  Requires K % 96 == 0
// (K = 768 / 384 / 1536 at call sites).
// LDS tile layout per buffer: 16B slot s of a 64-row block holds
//   (row = s>>2, kgroup = (s&3) ^ ((s>>3)&3))   [XOR swizzle, conflict-free]
// EPI: 3 = bf16 gelu_fast(acc+bias) -> Cb
//      4 = plain f32 acc -> Cf (split-K partial; bias/res added in LN2)
//      5 = fused QKV routing: nn<768 -> Cb=q (*0.125); <1536 -> Cb2=k;
//          else Cb3 = v^T per-head [((b*NH+h)*DH+d)*SEQ+s]
// XS: 1 = XCD-aware block swizzle (requires gridDim.y % 8 == 0)
#define STAGE3(DA, DB, KK) do {                                                \
    const int kk_ = ((KK) < K) ? (KK) : (K - 32);                              \
    _Pragma("unroll")                                                          \
    for (int p = 0; p < BM/64; p++)                                            \
      async_copy16(gA + (size_t)p * 64 * sA + kk_,                             \
                   &DA[(wave*16)*32 + p*64*32]);                               \
    _Pragma("unroll")                                                          \
    for (int p = 0; p < BN/64; p++)                                            \
      async_copy16(gB + (size_t)p * 64 * sB + kk_,                             \
                   &DB[(wave*16)*32 + p*64*32]);                               \
  } while (0)

#define COMP3(SA, SB) do {                                                     \
    bf16x8 af[MT], bfv[NT];                                                    \
    _Pragma("unroll")                                                          \
    for (int i = 0; i < MT; i++)                                               \
      af[i] = *(const bf16x8*)&SA[(wm*(MT*16) + i*16 + l16) * 32               \
                                  + (quad ^ swz) * 8];                         \
    _Pragma("unroll")                                                          \
    for (int j = 0; j < NT; j++)                                               \
      bfv[j] = *(const bf16x8*)&SB[(wn*(NT*16) + j*16 + l16) * 32              \
                                   + (quad ^ swz) * 8];                        \
    __builtin_amdgcn_s_setprio(1);                                             \
    _Pragma("unroll")                                                          \
    for (int i = 0; i < MT; i++)                                               \
      _Pragma("unroll")                                                        \
      for (int j = 0; j < NT; j++)                                             \
        acc[i][j] = __builtin_amdgcn_mfma_f32_16x16x32_bf16(                   \
            af[i], bfv[j], acc[i][j], 0, 0, 0);                                \
    __builtin_amdgcn_s_setprio(0);                                             \
  } while (0)

#define PIPE_STEP(SA, SB, DA, DB, KK) do {                                     \
    STAGE3(DA, DB, KK);                                                        \
    asm volatile("s_waitcnt vmcnt(4)" ::: "memory");                           \
    __builtin_amdgcn_s_barrier();                                              \
    COMP3(SA, SB);                                                             \
    __builtin_amdgcn_s_barrier();                                              \
  } while (0)

template<int BM, int BN, int MT, int NT, int EPI, int XS>
__global__ __launch_bounds__(256, 3)
void gemm_bt(const bf16* __restrict__ A, const bf16* __restrict__ Bt,
             float* __restrict__ Cf, float* __restrict__ Cf2,
             bf16* __restrict__ Cb, bf16* __restrict__ Cb2,
             bf16* __restrict__ Cb3,
             const bf16* __restrict__ bias, const bf16* __restrict__ res,
             int K, int sA, int sB, int sC, int ksplit)
{
  __shared__ __align__(16) bf16 A0[BM*32];
  __shared__ __align__(16) bf16 B0[BN*32];
  __shared__ __align__(16) bf16 A1[BM*32];
  __shared__ __align__(16) bf16 B1[BN*32];
  __shared__ __align__(16) bf16 A2[BM*32];
  __shared__ __align__(16) bf16 B2[BN*32];
  const int tid  = threadIdx.x;
  const int wave = tid >> 6;
  const int lane = tid & 63;
  const int quad = lane >> 4;
  const int l16  = lane & 15;
  const int wm = wave >> 1, wn = wave & 1;   // 2x2 wave grid
  const int swz = (l16 >> 1) & 3;            // read-side XOR swizzle key

  // split-K: z=1 takes the upper K-half and writes partials to Cf2
  if (ksplit && blockIdx.z) { A += ksplit; Bt += ksplit; Cf = Cf2; }

  int bx = blockIdx.x, by = blockIdx.y;
  if (XS) {
    if ((gridDim.y & 7) == 0) {
      const int id  = by * gridDim.x + bx;
      const int xcd = id & 7, slot = id >> 3;
      bx = slot % gridDim.x;
      by = (slot / gridDim.x) * 8 + xcd;
    }
  }
  const int m0 = by * BM;
  const int n0 = bx * BN;
  const int srow = tid >> 2;
  const int scol = (((tid & 3) ^ ((tid >> 3) & 3))) * 8;   // swizzled gather

  const bf16* gA = A + (size_t)(m0 + srow) * sA + scol;
  const bf16* gB = Bt + (size_t)(n0 + srow) * sB + scol;

  f32x4 acc[MT][NT];
  const f32x4 fzero = {0.f, 0.f, 0.f, 0.f};
#pragma unroll
  for (int i = 0; i < MT; i++)
#pragma unroll
    for (int j = 0; j < NT; j++) acc[i][j] = fzero;

  // ---- 3-stage software pipeline, depth 2 (K % 96 == 0) ----
  STAGE3(A0, B0, 0);
  STAGE3(A1, B1, 32);
  for (int k0 = 0; k0 < K; k0 += 96) {
    PIPE_STEP(A0, B0, A2, B2, k0 + 64);
    PIPE_STEP(A1, B1, A0, B0, k0 + 96);
    PIPE_STEP(A2, B2, A1, B1, k0 + 128);
  }
  asm volatile("s_waitcnt vmcnt(0)" ::: "memory");   // drain redundant tail DMA

  // epilogue: C/D layout col=lane&15, row=quad*4+reg
#pragma unroll
  for (int i = 0; i < MT; i++) {
    const int mtile = m0 + wm*(MT*16) + i*16 + quad*4;
#pragma unroll
    for (int j = 0; j < NT; j++) {
      const int nn = n0 + wn*(NT*16) + j*16 + l16;
      if (EPI == 5) {
        const float bv = (float)bias[nn];
        if (nn < HDIM) {
#pragma unroll
          for (int r = 0; r < 4; r++)
            Cb[(size_t)(mtile + r) * HDIM + nn] = (bf16)((acc[i][j][r] + bv) * 0.125f);
        } else if (nn < 2*HDIM) {
#pragma unroll
          for (int r = 0; r < 4; r++)
            Cb2[(size_t)(mtile + r) * HDIM + (nn - HDIM)] = (bf16)(acc[i][j][r] + bv);
        } else {
          const int nn2 = nn - 2*HDIM;
          const int bb = mtile >> 9, s = mtile & 511;
          const int hh = nn2 >> 6, dd = nn2 & 63;
          const size_t base = ((size_t)(bb*NHEAD + hh) * DHEAD + dd) * SEQ + s;
          bf16x4 pk;
#pragma unroll
          for (int r = 0; r < 4; r++) pk[r] = (bf16)(acc[i][j][r] + bv);
          *(bf16x4*)(Cb3 + base) = pk;
        }
      } else if (EPI == 3) {
        const float bv = (float)bias[nn];
#pragma unroll
        for (int r = 0; r < 4; r++)
          Cb[(size_t)(mtile + r) * sC + nn] = (bf16)gelu_fast(acc[i][j][r] + bv);
      } else if (EPI == 4) {
#pragma unroll
        for (int r = 0; r < 4; r++)
          Cf[(size_t)(mtile + r) * sC + nn] = acc[i][j][r];
      }
    }
  }
}

// =====================  fused flash attention  =====================
__global__ __launch_bounds__(256)
void flash_k(const bf16* __restrict__ qb, const bf16* __restrict__ kb,
             const bf16* __restrict__ vt, bf16* __restrict__ ctxb)
{
  __shared__ __align__(16) bf16 Qs[128][72];
  __shared__ __align__(16) bf16 Ks[64][72];
  __shared__ __align__(16) bf16 Vs[64][72];
  __shared__ __align__(16) bf16 Ps[128][72];
  const int tid = threadIdx.x;
  const int wave = tid >> 6, lane = tid & 63;
  const int quad = lane >> 4, l16 = lane & 15;
  const int z = blockIdx.y;
  const int b = z / NHEAD, h = z - b * NHEAD;
  const int qt = blockIdx.x;
  const size_t qRow0 = (size_t)b * SEQ + qt * 128;

#pragma unroll
  for (int r = 0; r < 4; r++) {
    const int idx = tid + r * 256;
    const int row = idx >> 3, c8 = (idx & 7) * 8;
    *(bf16x8*)&Qs[row][c8] =
        *(const bf16x8*)&qb[(qRow0 + row) * HDIM + h * DHEAD + c8];
  }

  f32x4 Oacc[2][4];
  float mrow[2][4], lrow[2][4];
#pragma unroll
  for (int i = 0; i < 2; i++)
#pragma unroll
    for (int n = 0; n < 4; n++) Oacc[i][n] = (f32x4){0.f,0.f,0.f,0.f};
#pragma unroll
  for (int i = 0; i < 2; i++)
#pragma unroll
    for (int r = 0; r < 4; r++) { mrow[i][r] = -3.0e38f; lrow[i][r] = 0.f; }

  for (int j = 0; j < 8; j++) {
    __syncthreads();
#pragma unroll
    for (int r = 0; r < 2; r++) {
      const int idx = tid + r * 256;
      const int row = idx >> 3, c8 = (idx & 7) * 8;
      *(bf16x8*)&Ks[row][c8] =
          *(const bf16x8*)&kb[((size_t)b*SEQ + j*64 + row) * HDIM + h*DHEAD + c8];
      *(bf16x8*)&Vs[row][c8] =
          *(const bf16x8*)&vt[((size_t)z*DHEAD + row) * SEQ + j*64 + c8];
    }
    __syncthreads();

    f32x4 Sacc[2][4];
#pragma unroll
    for (int i = 0; i < 2; i++)
#pragma unroll
      for (int n = 0; n < 4; n++) Sacc[i][n] = (f32x4){0.f,0.f,0.f,0.f};
#pragma unroll
    for (int kk = 0; kk < 2; kk++) {
      bf16x8 af[2], bv[4];
#pragma unroll
      for (int i = 0; i < 2; i++)
        af[i] = *(const bf16x8*)&Qs[wave*32 + i*16 + l16][kk*32 + quad*8];
#pragma unroll
      for (int n = 0; n < 4; n++)
        bv[n] = *(const bf16x8*)&Ks[n*16 + l16][kk*32 + quad*8];
#pragma unroll
      for (int i = 0; i < 2; i++)
#pragma unroll
        for (int n = 0; n < 4; n++)
          Sacc[i][n] = __builtin_amdgcn_mfma_f32_16x16x32_bf16(af[i], bv[n], Sacc[i][n], 0,0,0);
    }

    float alpha[2][4];
#pragma unroll
    for (int i = 0; i < 2; i++)
#pragma unroll
      for (int r = 0; r < 4; r++) {
        float mx = Sacc[i][0][r];
#pragma unroll
        for (int n = 1; n < 4; n++) mx = fmaxf(mx, Sacc[i][n][r]);
#pragma unroll
        for (int o = 8; o; o >>= 1) mx = fmaxf(mx, __shfl_xor(mx, o));
        const float mn = fmaxf(mrow[i][r], mx);
        const float a = __expf(mrow[i][r] - mn);
        float rs = 0.f;
#pragma unroll
        for (int n = 0; n < 4; n++) {
          const float p = __expf(Sacc[i][n][r] - mn);
          Sacc[i][n][r] = p; rs += p;
        }
#pragma unroll
        for (int o = 8; o; o >>= 1) rs += __shfl_xor(rs, o);
        lrow[i][r] = lrow[i][r] * a + rs;
        mrow[i][r] = mn;
        alpha[i][r] = a;
      }

#pragma unroll
    for (int i = 0; i < 2; i++)
#pragma unroll
      for (int n = 0; n < 4; n++)
#pragma unroll
        for (int r = 0; r < 4; r++)
          Ps[wave*32 + i*16 + quad*4 + r][n*16 + l16] = (bf16)Sacc[i][n][r];
    __syncthreads();

#pragma unroll
    for (int i = 0; i < 2; i++)
#pragma unroll
      for (int n = 0; n < 4; n++)
#pragma unroll
        for (int r = 0; r < 4; r++) Oacc[i][n][r] *= alpha[i][r];
#pragma unroll
    for (int kk = 0; kk < 2; kk++) {
      bf16x8 af[2], bv[4];
#pragma unroll
      for (int i = 0; i < 2; i++)
        af[i] = *(const bf16x8*)&Ps[wave*32 + i*16 + l16][kk*32 + quad*8];
#pragma unroll
      for (int n = 0; n < 4; n++)
        bv[n] = *(const bf16x8*)&Vs[n*16 + l16][kk*32 + quad*8];
#pragma unroll
      for (int i = 0; i < 2; i++)
#pragma unroll
        for (int n = 0; n < 4; n++)
          Oacc[i][n] = __builtin_amdgcn_mfma_f32_16x16x32_bf16(af[i], bv[n], Oacc[i][n], 0,0,0);
    }
  }

#pragma unroll
  for (int i = 0; i < 2; i++)
#pragma unroll
    for (int r = 0; r < 4; r++) {
      const float inv = 1.f / lrow[i][r];
      const size_t tok = qRow0 + wave*32 + i*16 + quad*4 + r;
#pragma unroll
      for (int n = 0; n < 4; n++)
        ctxb[tok * HDIM + h*DHEAD + n*16 + l16] = (bf16)(Oacc[i][n][r] * inv);
    }
}

// ==  LayerNorm over H=768 of (xa + xb + bias + res), bf16 out (+opt d_out) ==
// Consumes the two split-K partials; folds bias + residual add for free.
__global__ void layernorm2_k(const float* __restrict__ xa, const float* __restrict__ xb,
                             const bf16* __restrict__ bias, const bf16* __restrict__ res,
                             const bf16* __restrict__ g, const bf16* __restrict__ b,
                             bf16* __restrict__ yb, void* __restrict__ dout,
                             int last, const int* __restrict__ flag)
{
  __shared__ float sred[4];
  const int row = blockIdx.x;
  const int tid = threadIdx.x;
  const size_t base = (size_t)row * HDIM;
  const float v0 = xa[base+tid]     + xb[base+tid]     + (float)bias[tid]     + (float)res[base+tid];
  const float v1 = xa[base+tid+256] + xb[base+tid+256] + (float)bias[tid+256] + (float)res[base+tid+256];
  const float v2 = xa[base+tid+512] + xb[base+tid+512] + (float)bias[tid+512] + (float)res[base+tid+512];
  float s = v0 + v1 + v2;
#pragma unroll
  for (int o = 32; o; o >>= 1) s += __shfl_xor(s, o);
  if ((tid & 63) == 0) sred[tid >> 6] = s;
  __syncthreads();
  const float mean = (sred[0]+sred[1]+sred[2]+sred[3]) * (1.f/768.f);
  __syncthreads();
  const float d0 = v0-mean, d1 = v1-mean, d2 = v2-mean;
  float vs = d0*d0 + d1*d1 + d2*d2;
#pragma unroll
  for (int o = 32; o; o >>= 1) vs += __shfl_xor(vs, o);
  if ((tid & 63) == 0) sred[tid >> 6] = vs;
  __syncthreads();
  const float var = (sred[0]+sred[1]+sred[2]+sred[3]) * (1.f/768.f);
  const float rs  = rsqrtf(var + 1e-12f);
  const float y0 = d0*rs*(float)g[tid]     + (float)b[tid];
  const float y1 = d1*rs*(float)g[tid+256] + (float)b[tid+256];
  const float y2 = d2*rs*(float)g[tid+512] + (float)b[tid+512];
  bf16* ybr = yb + base;
  ybr[tid]     = (bf16)y0;
  ybr[tid+256] = (bf16)y1;
  ybr[tid+512] = (bf16)y2;
  if (last) {
    if (*flag) {
      float* o = (float*)dout + base;
      o[tid] = y0; o[tid+256] = y1; o[tid+512] = y2;
    } else {
      bf16* o = (bf16*)dout + base;
      o[tid] = (bf16)y0; o[tid+256] = (bf16)y1; o[tid+512] = (bf16)y2;
    }
  }
}

// ============================================================================
extern "C" void kernel_launch(void* const* d_in, const int* in_sizes, int n_in,
                              void* d_out, int out_size, void* d_ws, size_t ws_size,
                              hipStream_t stream)
{
  (void)in_sizes; (void)n_in; (void)out_size;

  char* ws = (char*)d_ws;
  size_t off = 0;
  auto carve = [&](size_t bytes) -> char* {
    char* p = ws + off; off += (bytes + 255) & ~(size_t)255; return p;
  };
  int*   flag = (int*)carve(256);
  bf16*  hcur = (bf16*)carve((size_t)MTOK*HDIM*2);
  bf16*  qb   = (bf16*)carve((size_t)MTOK*HDIM*2);
  bf16*  kb   = (bf16*)carve((size_t)MTOK*HDIM*2);
  bf16*  vt   = (bf16*)carve((size_t)MTOK*HDIM*2);
  bf16*  ctxb = (bf16*)carve((size_t)MTOK*HDIM*2);
  float* x1   = (float*)carve((size_t)MTOK*HDIM*4);
  float* x2   = (float*)carve((size_t)MTOK*HDIM*4);   // split-K partial #2
  bf16*  aob  = kb;   // kb dead once flash attention of the layer is complete

  bf16* nbqkv = (bf16*)carve((size_t)LNUM*NQKV*2);
  bf16* nbo   = (bf16*)carve((size_t)LNUM*HDIM*2);
  bf16* ng1   = (bf16*)carve((size_t)LNUM*HDIM*2);
  bf16* nb1   = (bf16*)carve((size_t)LNUM*HDIM*2);
  bf16* nbi   = (bf16*)carve((size_t)LNUM*IDIM*2);
  bf16* nbo2  = (bf16*)carve((size_t)LNUM*HDIM*2);
  bf16* ng2   = (bf16*)carve((size_t)LNUM*HDIM*2);
  bf16* nb2   = (bf16*)carve((size_t)LNUM*HDIM*2);

  const size_t wAllBytes = (size_t)LNUM*(NQKV*HDIM + HDIM*HDIM + 2*HDIM*IDIM)*2; // ~84.9MB
  const bool preAll = ws_size >= off + wAllBytes + (size_t)256*IDIM*2 + (1u<<20);
  bf16 *wqkvt=0, *wot=0, *wit=0, *wo2t=0, *bufA=0, *bufB=0;
  if (preAll) {
    wqkvt = (bf16*)carve((size_t)LNUM*NQKV*HDIM*2);
    wot   = (bf16*)carve((size_t)LNUM*HDIM*HDIM*2);
    wit   = (bf16*)carve((size_t)LNUM*HDIM*IDIM*2);
    wo2t  = (bf16*)carve((size_t)LNUM*HDIM*IDIM*2);
  } else {
    bufA = (bf16*)carve((size_t)HDIM*IDIM*2);
    bufB = (bf16*)carve((size_t)HDIM*IDIM*2);
  }

  const size_t unionAvail = (ws_size > off) ? (ws_size - off) : 0;
  int RM = 256;
  { const int rms[6] = {8192,4096,2048,1024,512,256};
    for (int i = 0; i < 6; i++)
      if ((size_t)rms[i]*IDIM*2 <= unionAvail) { RM = rms[i]; break; } }
  bf16* interb = (bf16*)(ws + off);

  // ---------------- normalize inputs ----------------------------------------
  detect_k<<<1, 256, 0, stream>>>((const unsigned short*)d_in[1], flag);
  cvt1d_k<<<(MTOK*HDIM+255)/256, 256, 0, stream>>>(d_in[0], hcur, MTOK*HDIM, flag);
  cvt_slice_k<<<(LNUM*HDIM+255)/256, 256, 0, stream>>>(d_in[2], nbqkv, HDIM, 0,      NQKV, LNUM*HDIM, flag);
  cvt_slice_k<<<(LNUM*HDIM+255)/256, 256, 0, stream>>>(d_in[4], nbqkv, HDIM, HDIM,   NQKV, LNUM*HDIM, flag);
  cvt_slice_k<<<(LNUM*HDIM+255)/256, 256, 0, stream>>>(d_in[6], nbqkv, HDIM, 2*HDIM, NQKV, LNUM*HDIM, flag);
  cvt1d_k<<<(LNUM*HDIM+255)/256, 256, 0, stream>>>(d_in[8],  nbo,  LNUM*HDIM, flag);
  cvt1d_k<<<(LNUM*HDIM+255)/256, 256, 0, stream>>>(d_in[9],  ng1,  LNUM*HDIM, flag);
  cvt1d_k<<<(LNUM*HDIM+255)/256, 256, 0, stream>>>(d_in[10], nb1,  LNUM*HDIM, flag);
  cvt1d_k<<<(LNUM*IDIM+255)/256, 256, 0, stream>>>(d_in[12], nbi,  LNUM*IDIM, flag);
  cvt1d_k<<<(LNUM*HDIM+255)/256, 256, 0, stream>>>(d_in[14], nbo2, LNUM*HDIM, flag);
  cvt1d_k<<<(LNUM*HDIM+255)/256, 256, 0, stream>>>(d_in[15], ng2,  LNUM*HDIM, flag);
  cvt1d_k<<<(LNUM*HDIM+255)/256, 256, 0, stream>>>(d_in[16], nb2,  LNUM*HDIM, flag);

  const dim3 tb(32, 8);
  if (preAll) {
    wtrans_k<<<dim3(HDIM/32, HDIM/32, LNUM), tb, 0, stream>>>(d_in[1], wqkvt, HDIM, HDIM, 0, NQKV*HDIM, 0,           flag);
    wtrans_k<<<dim3(HDIM/32, HDIM/32, LNUM), tb, 0, stream>>>(d_in[3], wqkvt, HDIM, HDIM, 0, NQKV*HDIM, HDIM*HDIM,   flag);
    wtrans_k<<<dim3(HDIM/32, HDIM/32, LNUM), tb, 0, stream>>>(d_in[5], wqkvt, HDIM, HDIM, 0, NQKV*HDIM, 2*HDIM*HDIM, flag);
    wtrans_k<<<dim3(HDIM/32, HDIM/32, LNUM), tb, 0, stream>>>(d_in[7], wot,  HDIM, HDIM, 0, HDIM*HDIM, 0, flag);
    wtrans_k<<<dim3(IDIM/32, HDIM/32, LNUM), tb, 0, stream>>>(d_in[11], wit,  HDIM, IDIM, 0, HDIM*IDIM, 0, flag);
    wtrans_k<<<dim3(HDIM/32, IDIM/32, LNUM), tb, 0, stream>>>(d_in[13], wo2t, IDIM, HDIM, 0, HDIM*IDIM, 0, flag);
  }

  for (int l = 0; l < LNUM; l++) {
    const bf16* hin = hcur;

    // ---- fused QKV ----
    const bf16* WqkvT;
    if (preAll) WqkvT = wqkvt + (size_t)l * NQKV * HDIM;
    else {
      wtrans_k<<<dim3(HDIM/32, HDIM/32, 1), tb, 0, stream>>>(d_in[1], bufA, HDIM, HDIM, l, 0, 0,           flag);
      wtrans_k<<<dim3(HDIM/32, HDIM/32, 1), tb, 0, stream>>>(d_in[3], bufA, HDIM, HDIM, l, 0, HDIM*HDIM,   flag);
      wtrans_k<<<dim3(HDIM/32, HDIM/32, 1), tb, 0, stream>>>(d_in[5], bufA, HDIM, HDIM, l, 0, 2*HDIM*HDIM, flag);
      WqkvT = bufA;
    }
    gemm_bt<128,128,4,4,5,1><<<dim3(NQKV/128, MTOK/128), 256, 0, stream>>>(
        hin, WqkvT, nullptr, nullptr, qb, kb, vt, nbqkv + (size_t)l*NQKV, nullptr,
        HDIM, HDIM, HDIM, HDIM, 0);

    // ---- fused flash attention ----
    flash_k<<<dim3(SEQ/128, NB*NHEAD), 256, 0, stream>>>(qb, kb, vt, ctxb);

    // ---- x1+x2 = ctx@Wo (split-K x2, 768 blocks = 100% fill) ----
    const bf16* WoT;
    if (preAll) WoT = wot + (size_t)l * HDIM * HDIM;
    else {
      wtrans_k<<<dim3(HDIM/32, HDIM/32, 1), tb, 0, stream>>>(d_in[7], bufA, HDIM, HDIM, l, 0, 0, flag);
      WoT = bufA;
    }
    gemm_bt<128,128,4,4,4,1><<<dim3(HDIM/128, MTOK/128, 2), 256, 0, stream>>>(
        ctxb, WoT, x1, x2, nullptr, nullptr, nullptr, nullptr, nullptr,
        HDIM/2, HDIM, HDIM, HDIM, HDIM/2);
    layernorm2_k<<<MTOK, 256, 0, stream>>>(x1, x2, nbo + l*HDIM, hin,
                                           ng1 + l*HDIM, nb1 + l*HDIM, aob,
                                           d_out, 0, flag);

    // ---- FFN ----
    const bf16 *WiT, *Wo2T;
    if (preAll) { WiT = wit + (size_t)l*HDIM*IDIM; Wo2T = wo2t + (size_t)l*HDIM*IDIM; }
    else {
      wtrans_k<<<dim3(IDIM/32, HDIM/32, 1), tb, 0, stream>>>(d_in[11], bufA, HDIM, IDIM, l, 0, 0, flag);
      wtrans_k<<<dim3(HDIM/32, IDIM/32, 1), tb, 0, stream>>>(d_in[13], bufB, IDIM, HDIM, l, 0, 0, flag);
      WiT = bufA; Wo2T = bufB;
    }
    for (int r0 = 0; r0 < MTOK; r0 += RM) {
      gemm_bt<128,128,4,4,3,1><<<dim3(IDIM/128, RM/128), 256, 0, stream>>>(
          aob + (size_t)r0*HDIM, WiT, nullptr, nullptr, interb, nullptr, nullptr,
          nbi + (size_t)l*IDIM, nullptr, HDIM, HDIM, HDIM, IDIM, 0);
      gemm_bt<128,128,4,4,4,1><<<dim3(HDIM/128, RM/128, 2), 256, 0, stream>>>(
          interb, Wo2T, x1 + (size_t)r0*HDIM, x2 + (size_t)r0*HDIM,
          nullptr, nullptr, nullptr, nullptr, nullptr,
          IDIM/2, IDIM, IDIM, HDIM, IDIM/2);
    }
    layernorm2_k<<<MTOK, 256, 0, stream>>>(x1, x2, nbo2 + l*HDIM, aob,
                                           ng2 + l*HDIM, nb2 + l*HDIM, hcur,
                                           d_out, (l == LNUM-1) ? 1 : 0, flag);
  }
}